// Round 1
// baseline (8347.737 us; speedup 1.0000x reference)
//
#include <hip/hip_runtime.h>
#include <math.h>

#define N_NODES 50000
#define N_EDGES 1600000
#define DIM     128
#define RCUT    5.0f
#define DEPTH   3

// ---------------------------------------------------------------------------
// f[i] = exp(-(r-rs)^2/sigma^2) * 0.5*cos(pi*r/rc) * (r < rc)
// ---------------------------------------------------------------------------
__global__ void envelope_kernel(const float* __restrict__ e,
                                const float* __restrict__ rs,
                                const float* __restrict__ sigma,
                                float* __restrict__ f) {
    int i = blockIdx.x * blockDim.x + threadIdx.x;
    if (i >= N_EDGES) return;
    float r  = e[i];
    float d  = r - rs[0];
    float sg = sigma[0];
    float gauss = expf(-(d * d) / (sg * sg));
    float cut   = 0.5f * cosf(r * (float)(M_PI / (double)RCUT));
    cut = (r < RCUT) ? cut : 0.0f;
    f[i] = gauss * cut;
}

// ---------------------------------------------------------------------------
// svf[dst[e]] += f[e] * cur[src[e]]   (svf pre-initialized with v -> skip add)
// 32 threads per edge, float4 per thread.
// ---------------------------------------------------------------------------
__global__ void scatter_kernel(const float* __restrict__ cur,
                               const float* __restrict__ f,
                               const int*   __restrict__ src,
                               const int*   __restrict__ dst,
                               float* __restrict__ svf) {
    long long gid = (long long)blockIdx.x * blockDim.x + threadIdx.x;
    int e    = (int)(gid >> 5);
    int lane = (int)(gid & 31);
    if (e >= N_EDGES) return;
    int   s  = src[e];
    int   d  = dst[e];
    float fe = f[e];
    const float4* vs = (const float4*)(cur + (size_t)s * DIM);
    float4 val = vs[lane];
    float* o = svf + (size_t)d * DIM + lane * 4;
    atomicAdd(o + 0, fe * val.x);
    atomicAdd(o + 1, fe * val.y);
    atomicAdd(o + 2, fe * val.z);
    atomicAdd(o + 3, fe * val.w);
}

// ---------------------------------------------------------------------------
// out = relu(x @ A^T + b), x = svf (already contains +v), [N,128]x[128,128].
// 8 rows/block, 256 threads: thread (j = tid&127) computes 4 rows x 1 col.
// A^T staged in LDS in two 64-wide k tiles with XOR bank swizzle.
// ---------------------------------------------------------------------------
#define ROWS_PER_BLOCK 8
__global__ __launch_bounds__(256) void gemm_relu_kernel(
        const float* __restrict__ x,
        const float* __restrict__ Aw,
        const float* __restrict__ Ab,
        float* __restrict__ out) {
    __shared__ float At[64 * DIM];              // At[kk][j^(kk&31)] = Aw[j][half*64+kk]
    __shared__ float xs[ROWS_PER_BLOCK][DIM];   // 8 rows of x

    int tid  = threadIdx.x;
    int row0 = blockIdx.x * ROWS_PER_BLOCK;
    int j    = tid & 127;
    int hsel = tid >> 7;          // 0: rows 0..3, 1: rows 4..7

    float acc[4] = {0.f, 0.f, 0.f, 0.f};

    for (int half = 0; half < 2; ++half) {
        // stage A^T k-tile (swizzled, conflict-free write & read)
        for (int idx = tid; idx < 64 * DIM; idx += 256) {
            int jj = idx >> 6;       // output column 0..127
            int kk = idx & 63;       // k within tile
            At[kk * DIM + (jj ^ (kk & 31))] = Aw[jj * DIM + half * 64 + kk];
        }
        if (half == 0) {
            for (int idx = tid; idx < ROWS_PER_BLOCK * DIM; idx += 256)
                xs[idx >> 7][idx & 127] = x[(size_t)row0 * DIM + idx];
        }
        __syncthreads();

        #pragma unroll 8
        for (int kk = 0; kk < 64; ++kk) {
            float a = At[kk * DIM + (j ^ (kk & 31))];
            int   k = half * 64 + kk;
            #pragma unroll
            for (int r = 0; r < 4; ++r)
                acc[r] = fmaf(a, xs[hsel * 4 + r][k], acc[r]);
        }
        __syncthreads();
    }

    float b = Ab[j];
    #pragma unroll
    for (int r = 0; r < 4; ++r) {
        float o = acc[r] + b;
        out[(size_t)(row0 + hsel * 4 + r) * DIM + j] = fmaxf(o, 0.0f);
    }
}

// ---------------------------------------------------------------------------
extern "C" void kernel_launch(void* const* d_in, const int* in_sizes, int n_in,
                              void* d_out, int out_size, void* d_ws, size_t ws_size,
                              hipStream_t stream) {
    const float* v     = (const float*)d_in[0];
    const float* e     = (const float*)d_in[1];
    const int*   src   = (const int*)  d_in[2];
    const int*   dst   = (const int*)  d_in[3];
    const float* Aw    = (const float*)d_in[4];
    const float* Ab    = (const float*)d_in[5];
    const float* rs    = (const float*)d_in[6];
    const float* sigma = (const float*)d_in[7];
    float* out = (float*)d_out;

    // workspace layout
    float* f   = (float*)d_ws;                       //  E floats   (6.4 MB)
    float* svf = f + N_EDGES;                        //  N*DIM      (25.6 MB)
    float* cur = svf + (size_t)N_NODES * DIM;        //  N*DIM      (25.6 MB)

    envelope_kernel<<<(N_EDGES + 255) / 256, 256, 0, stream>>>(e, rs, sigma, f);

    const float* curIn = v;
    const size_t nodeBytes = (size_t)N_NODES * DIM * sizeof(float);
    for (int depth = 0; depth < DEPTH; ++depth) {
        // svf = v  (folds the +v skip connection into the scatter target)
        hipMemcpyAsync(svf, v, nodeBytes, hipMemcpyDeviceToDevice, stream);

        long long totThreads = (long long)N_EDGES * 32;
        int blocks = (int)((totThreads + 255) / 256);
        scatter_kernel<<<blocks, 256, 0, stream>>>(curIn, f, src, dst, svf);

        float* o = (depth == DEPTH - 1) ? out : cur;
        gemm_relu_kernel<<<N_NODES / ROWS_PER_BLOCK, 256, 0, stream>>>(svf, Aw, Ab, o);
        curIn = cur;
    }
}

// Round 2
// 939.837 us; speedup vs baseline: 8.8821x; 8.8821x over previous
//
#include <hip/hip_runtime.h>
#include <math.h>

#define N_NODES 50000
#define N_EDGES 1600000
#define DIM     128
#define RCUT    5.0f
#define DEPTH   3
#define ROWS_PER_BLOCK 8
#define SCAN_THREADS 256

// ---------------------------------------------------------------------------
// Histogram of destination degrees: deg[dst[e]]++
// ---------------------------------------------------------------------------
__global__ void hist_kernel(const int* __restrict__ dst, int* __restrict__ deg) {
    int i = blockIdx.x * blockDim.x + threadIdx.x;
    if (i < N_EDGES) atomicAdd(&deg[dst[i]], 1);
}

// ---------------------------------------------------------------------------
// Single-block exclusive scan over deg (length N_NODES).
// Writes off[0..N] and converts deg array in-place into a running cursor
// (cursor[i] = off[i]) for the reorder pass.
// ---------------------------------------------------------------------------
__global__ __launch_bounds__(SCAN_THREADS) void scan_kernel(
        int* __restrict__ deg_cursor, int* __restrict__ off) {
    __shared__ int part[SCAN_THREADS];
    int tid = threadIdx.x;
    const int CH = (N_NODES + SCAN_THREADS - 1) / SCAN_THREADS;  // 196
    int beg = tid * CH;
    int end = beg + CH; if (end > N_NODES) end = N_NODES;

    int s = 0;
    for (int i = beg; i < end; ++i) s += deg_cursor[i];
    part[tid] = s;
    __syncthreads();
    // Hillis-Steele inclusive scan over 256 partials
    for (int d = 1; d < SCAN_THREADS; d <<= 1) {
        int val = (tid >= d) ? part[tid - d] : 0;
        __syncthreads();
        part[tid] += val;
        __syncthreads();
    }
    int run = (tid == 0) ? 0 : part[tid - 1];
    for (int i = beg; i < end; ++i) {
        int dg = deg_cursor[i];
        off[i] = run;
        deg_cursor[i] = run;   // becomes the reorder cursor
        run += dg;
    }
    if (tid == SCAN_THREADS - 1) off[N_NODES] = run;
}

// ---------------------------------------------------------------------------
// Reorder edges into CSR-by-dst; envelope f computed inline.
// meta[pos] = { src, bitcast(f) }
// ---------------------------------------------------------------------------
__global__ void reorder_kernel(const float* __restrict__ e,
                               const int*   __restrict__ src,
                               const int*   __restrict__ dst,
                               const float* __restrict__ rs,
                               const float* __restrict__ sigma,
                               int* __restrict__ cursor,
                               int2* __restrict__ meta) {
    int i = blockIdx.x * blockDim.x + threadIdx.x;
    if (i >= N_EDGES) return;
    float r  = e[i];
    float d  = r - rs[0];
    float sg = sigma[0];
    float gauss = expf(-(d * d) / (sg * sg));
    float cut   = 0.5f * cosf(r * (float)(M_PI / (double)RCUT));
    cut = (r < RCUT) ? cut : 0.0f;
    float fe = gauss * cut;
    int pos = atomicAdd(&cursor[dst[i]], 1);
    meta[pos] = make_int2(src[i], __float_as_int(fe));
}

// ---------------------------------------------------------------------------
// One GCN layer, fused: per dst node gather sum(f*cur[src]) + v, then
// relu(x @ A^T + b). 256 threads = 8 nodes (32 threads / node, float4 lane).
// ---------------------------------------------------------------------------
__global__ __launch_bounds__(256) void layer_kernel(
        const float* __restrict__ cur,
        const float* __restrict__ v,
        const int2*  __restrict__ meta,
        const int*   __restrict__ off,
        const float* __restrict__ Aw,
        const float* __restrict__ Ab,
        float* __restrict__ out) {
    __shared__ float At[64 * DIM];                          // 32 KB, swizzled
    __shared__ __align__(16) float xs[ROWS_PER_BLOCK][DIM]; // 4 KB

    int tid  = threadIdx.x;
    int g    = tid >> 5;          // node group 0..7
    int lane = tid & 31;          // float4 lane within node row
    int n    = blockIdx.x * ROWS_PER_BLOCK + g;

    // ---- gather phase: acc = v[n] + sum_e f[e] * cur[src[e]] ----
    float4 acc = *(const float4*)(v + (size_t)n * DIM + lane * 4);
    int beg = off[n], end = off[n + 1];
    for (int c = beg; c < end; c += 32) {
        int m = end - c; if (m > 32) m = 32;
        int2 ml = (lane < m) ? meta[c + lane] : make_int2(0, 0);
        for (int j = 0; j < m; ++j) {
            int   s  = __shfl(ml.x, j, 32);
            float fe = __int_as_float(__shfl(ml.y, j, 32));
            float4 row = *(const float4*)(cur + (size_t)s * DIM + lane * 4);
            acc.x = fmaf(fe, row.x, acc.x);
            acc.y = fmaf(fe, row.y, acc.y);
            acc.z = fmaf(fe, row.z, acc.z);
            acc.w = fmaf(fe, row.w, acc.w);
        }
    }
    ((float4*)(&xs[g][0]))[lane] = acc;

    // ---- gemm phase: out[n] = relu(xs @ A^T + b) ----
    int j    = tid & 127;
    int hsel = tid >> 7;          // 0: rows 0..3, 1: rows 4..7
    float a4[4] = {0.f, 0.f, 0.f, 0.f};

    for (int half = 0; half < 2; ++half) {
        __syncthreads();
        for (int idx = tid; idx < 64 * DIM; idx += 256) {
            int jj = idx >> 6;    // output column
            int kk = idx & 63;    // k within tile
            At[kk * DIM + (jj ^ (kk & 31))] = Aw[jj * DIM + half * 64 + kk];
        }
        __syncthreads();
        #pragma unroll 8
        for (int kk = 0; kk < 64; ++kk) {
            float a = At[kk * DIM + (j ^ (kk & 31))];
            int   k = half * 64 + kk;
            #pragma unroll
            for (int r = 0; r < 4; ++r)
                a4[r] = fmaf(a, xs[hsel * 4 + r][k], a4[r]);
        }
    }

    int row0 = blockIdx.x * ROWS_PER_BLOCK;
    float b = Ab[j];
    #pragma unroll
    for (int r = 0; r < 4; ++r) {
        float o = a4[r] + b;
        out[(size_t)(row0 + hsel * 4 + r) * DIM + j] = fmaxf(o, 0.0f);
    }
}

// ---------------------------------------------------------------------------
extern "C" void kernel_launch(void* const* d_in, const int* in_sizes, int n_in,
                              void* d_out, int out_size, void* d_ws, size_t ws_size,
                              hipStream_t stream) {
    const float* v     = (const float*)d_in[0];
    const float* e     = (const float*)d_in[1];
    const int*   src   = (const int*)  d_in[2];
    const int*   dst   = (const int*)  d_in[3];
    const float* Aw    = (const float*)d_in[4];
    const float* Ab    = (const float*)d_in[5];
    const float* rs    = (const float*)d_in[6];
    const float* sigma = (const float*)d_in[7];
    float* out = (float*)d_out;

    // workspace layout (~38.8 MB; round 1 proved >= 57.6 MB available)
    int2*  meta   = (int2*)d_ws;                       // E * 8 B   (12.8 MB)
    float* bufA   = (float*)(meta + N_EDGES);          // N*DIM fp32 (25.6 MB)
    int*   off    = (int*)(bufA + (size_t)N_NODES * DIM); // N+1
    int*   cursor = off + (N_NODES + 1);               // N

    const int EB = (N_EDGES + 255) / 256;

    hipMemsetAsync(cursor, 0, N_NODES * sizeof(int), stream);
    hist_kernel<<<EB, 256, 0, stream>>>(dst, cursor);
    scan_kernel<<<1, SCAN_THREADS, 0, stream>>>(cursor, off);
    reorder_kernel<<<EB, 256, 0, stream>>>(e, src, dst, rs, sigma, cursor, meta);

    const int NB = N_NODES / ROWS_PER_BLOCK;  // 6250
    // layer 0: v -> bufA ; layer 1: bufA -> out ; layer 2: out -> bufA
    layer_kernel<<<NB, 256, 0, stream>>>(v,    v, meta, off, Aw, Ab, bufA);
    layer_kernel<<<NB, 256, 0, stream>>>(bufA, v, meta, off, Aw, Ab, out);
    layer_kernel<<<NB, 256, 0, stream>>>(out,  v, meta, off, Aw, Ab, bufA);
    hipMemcpyAsync(out, bufA, (size_t)N_NODES * DIM * sizeof(float),
                   hipMemcpyDeviceToDevice, stream);
}

// Round 3
// 847.791 us; speedup vs baseline: 9.8465x; 1.1086x over previous
//
#include <hip/hip_runtime.h>
#include <math.h>

#define N_NODES 50000
#define N_EDGES 1600000
#define DIM     128
#define RCUT    5.0f
#define SCAN_THREADS 256
#define LAYER_BLOCKS 1280
#define N_PAIRS (N_NODES / 2)

// ---------------- bf16 helpers ----------------
__device__ __forceinline__ float bf_lo(unsigned int u) { return __uint_as_float(u << 16); }
__device__ __forceinline__ float bf_hi(unsigned int u) { return __uint_as_float(u & 0xffff0000u); }
__device__ __forceinline__ unsigned short f2bf(float x) {
    unsigned int u = __float_as_uint(x);
    u += 0x7fffu + ((u >> 16) & 1u);   // round to nearest even
    return (unsigned short)(u >> 16);
}

// ---------------- v (fp32) -> vb (bf16) ----------------
__global__ void convert_v_kernel(const float* __restrict__ v,
                                 unsigned short* __restrict__ vb) {
    int i = blockIdx.x * blockDim.x + threadIdx.x;   // one float4 -> ushort4
    if (i >= N_NODES * DIM / 4) return;
    float4 x = ((const float4*)v)[i];
    ushort4 o;
    o.x = f2bf(x.x); o.y = f2bf(x.y); o.z = f2bf(x.z); o.w = f2bf(x.w);
    ((ushort4*)vb)[i] = o;
}

// ---------------- degree histogram + per-edge slot ----------------
__global__ void hist_kernel(const int* __restrict__ dst,
                            int* __restrict__ deg,
                            unsigned short* __restrict__ pos) {
    int i = blockIdx.x * blockDim.x + threadIdx.x;
    if (i < N_EDGES) pos[i] = (unsigned short)atomicAdd(&deg[dst[i]], 1);
}

// ---------------- single-block exclusive scan ----------------
__global__ __launch_bounds__(SCAN_THREADS) void scan_kernel(
        const int* __restrict__ deg, int* __restrict__ off) {
    __shared__ int part[SCAN_THREADS];
    int tid = threadIdx.x;
    const int CH = (N_NODES + SCAN_THREADS - 1) / SCAN_THREADS;
    int beg = tid * CH;
    int end = beg + CH; if (end > N_NODES) end = N_NODES;
    int s = 0;
    for (int i = beg; i < end; ++i) s += deg[i];
    part[tid] = s;
    __syncthreads();
    for (int d = 1; d < SCAN_THREADS; d <<= 1) {
        int val = (tid >= d) ? part[tid - d] : 0;
        __syncthreads();
        part[tid] += val;
        __syncthreads();
    }
    int run = (tid == 0) ? 0 : part[tid - 1];
    for (int i = beg; i < end; ++i) { off[i] = run; run += deg[i]; }
    if (tid == SCAN_THREADS - 1) off[N_NODES] = run;
}

// ---------------- reorder (atomic-free) + fused envelope ----------------
__global__ void reorder_kernel(const float* __restrict__ e,
                               const int*   __restrict__ src,
                               const int*   __restrict__ dst,
                               const float* __restrict__ rs,
                               const float* __restrict__ sigma,
                               const int*   __restrict__ off,
                               const unsigned short* __restrict__ pos,
                               int2* __restrict__ meta) {
    int i = blockIdx.x * blockDim.x + threadIdx.x;
    if (i >= N_EDGES) return;
    float r  = e[i];
    float d  = r - rs[0];
    float sg = sigma[0];
    float gauss = expf(-(d * d) / (sg * sg));
    float cut   = 0.5f * cosf(r * (float)(M_PI / (double)RCUT));
    cut = (r < RCUT) ? cut : 0.0f;
    float fe = gauss * cut;
    meta[off[dst[i]] + (int)pos[i]] = make_int2(src[i], __float_as_int(fe));
}

// ---------------- fused layer: gather(bf16) + GEMM + relu ----------------
// Persistent blocks. Wave = 2 nodes (32 lanes each, lane owns 4 dims).
// At (A^T, bf16, k-major) staged once per block: 32 KB LDS, one barrier total.
__global__ __launch_bounds__(256) void layer_kernel(
        const unsigned short* __restrict__ cur,  // bf16 node feats [N, DIM]
        const float* __restrict__ v,             // fp32 skip       [N, DIM]
        const int2*  __restrict__ meta,
        const int*   __restrict__ off,
        const float* __restrict__ Aw,
        const float* __restrict__ Ab,
        unsigned short* __restrict__ out_bf,     // if !last
        float* __restrict__ out_f,               // if last
        int last) {
    __shared__ unsigned short At[DIM * DIM];     // At[k][j] = Aw[j][k], 32 KB

    int tid = threadIdx.x;
    for (int idx = tid; idx < DIM * DIM; idx += 256) {
        int j = idx & 127, k = idx >> 7;
        At[k * DIM + j] = f2bf(Aw[j * DIM + k]);
    }

    int lane32 = tid & 31;
    int group  = (tid >> 5) & 1;
    int gwave  = blockIdx.x * 4 + (tid >> 6);
    int j0     = lane32 * 4;
    float4 bias = *(const float4*)(Ab + j0);

    __syncthreads();

    for (int pair = gwave; pair < N_PAIRS; pair += LAYER_BLOCKS * 4) {
        int n = pair * 2 + group;

        // ---- gather: acc = v[n] + sum_e f[e]*cur[src[e]] ----
        float4 acc = *(const float4*)(v + (size_t)n * DIM + j0);
        int beg = off[n], end = off[n + 1];
        int c = beg;
        for (; c + 32 <= end; c += 32) {
            int2 ml = meta[c + lane32];
            #pragma unroll 8
            for (int jj = 0; jj < 32; ++jj) {
                int   s  = __shfl(ml.x, jj, 32);
                float fe = __int_as_float(__shfl(ml.y, jj, 32));
                uint2 r = *(const uint2*)(cur + (size_t)s * DIM + j0);
                acc.x = fmaf(fe, bf_lo(r.x), acc.x);
                acc.y = fmaf(fe, bf_hi(r.x), acc.y);
                acc.z = fmaf(fe, bf_lo(r.y), acc.z);
                acc.w = fmaf(fe, bf_hi(r.y), acc.w);
            }
        }
        int m = end - c;
        if (m > 0) {
            int2 ml = (lane32 < m) ? meta[c + lane32] : make_int2(0, 0);
            for (int jj = 0; jj < m; ++jj) {
                int   s  = __shfl(ml.x, jj, 32);
                float fe = __int_as_float(__shfl(ml.y, jj, 32));
                uint2 r = *(const uint2*)(cur + (size_t)s * DIM + j0);
                acc.x = fmaf(fe, bf_lo(r.x), acc.x);
                acc.y = fmaf(fe, bf_hi(r.x), acc.y);
                acc.z = fmaf(fe, bf_lo(r.y), acc.z);
                acc.w = fmaf(fe, bf_hi(r.y), acc.w);
            }
        }

        // ---- GEMM: out[n][j0..j0+3] = relu(sum_k x[k]*At[k][j] + b) ----
        // x[4*L+c] lives in lane L component c of acc -> shfl broadcast.
        float o0 = bias.x, o1 = bias.y, o2 = bias.z, o3 = bias.w;
        #pragma unroll 4
        for (int k0 = 0; k0 < 32; ++k0) {
            float x0 = __shfl(acc.x, k0, 32);
            float x1 = __shfl(acc.y, k0, 32);
            float x2 = __shfl(acc.z, k0, 32);
            float x3 = __shfl(acc.w, k0, 32);
            const unsigned short* ar = At + (4 * k0) * DIM + j0;
            uint2 a0 = *(const uint2*)(ar);
            uint2 a1 = *(const uint2*)(ar + DIM);
            uint2 a2 = *(const uint2*)(ar + 2 * DIM);
            uint2 a3 = *(const uint2*)(ar + 3 * DIM);
            o0 = fmaf(x0, bf_lo(a0.x), o0); o1 = fmaf(x0, bf_hi(a0.x), o1);
            o2 = fmaf(x0, bf_lo(a0.y), o2); o3 = fmaf(x0, bf_hi(a0.y), o3);
            o0 = fmaf(x1, bf_lo(a1.x), o0); o1 = fmaf(x1, bf_hi(a1.x), o1);
            o2 = fmaf(x1, bf_lo(a1.y), o2); o3 = fmaf(x1, bf_hi(a1.y), o3);
            o0 = fmaf(x2, bf_lo(a2.x), o0); o1 = fmaf(x2, bf_hi(a2.x), o1);
            o2 = fmaf(x2, bf_lo(a2.y), o2); o3 = fmaf(x2, bf_hi(a2.y), o3);
            o0 = fmaf(x3, bf_lo(a3.x), o0); o1 = fmaf(x3, bf_hi(a3.x), o1);
            o2 = fmaf(x3, bf_lo(a3.y), o2); o3 = fmaf(x3, bf_hi(a3.y), o3);
        }
        o0 = fmaxf(o0, 0.0f); o1 = fmaxf(o1, 0.0f);
        o2 = fmaxf(o2, 0.0f); o3 = fmaxf(o3, 0.0f);

        if (last) {
            float4 w; w.x = o0; w.y = o1; w.z = o2; w.w = o3;
            *(float4*)(out_f + (size_t)n * DIM + j0) = w;
        } else {
            ushort4 w;
            w.x = f2bf(o0); w.y = f2bf(o1); w.z = f2bf(o2); w.w = f2bf(o3);
            *(ushort4*)(out_bf + (size_t)n * DIM + j0) = w;
        }
    }
}

// ---------------------------------------------------------------------------
extern "C" void kernel_launch(void* const* d_in, const int* in_sizes, int n_in,
                              void* d_out, int out_size, void* d_ws, size_t ws_size,
                              hipStream_t stream) {
    const float* v     = (const float*)d_in[0];
    const float* e     = (const float*)d_in[1];
    const int*   src   = (const int*)  d_in[2];
    const int*   dst   = (const int*)  d_in[3];
    const float* Aw    = (const float*)d_in[4];
    const float* Ab    = (const float*)d_in[5];
    const float* rs    = (const float*)d_in[6];
    const float* sigma = (const float*)d_in[7];
    float* out = (float*)d_out;

    // workspace layout (~41.8 MB)
    int2*           meta = (int2*)d_ws;                               // 12.8 MB
    unsigned short* vb   = (unsigned short*)(meta + N_EDGES);         // 12.8 MB (reused as buf1)
    unsigned short* buf0 = vb + (size_t)N_NODES * DIM;                // 12.8 MB
    unsigned short* pos  = buf0 + (size_t)N_NODES * DIM;              //  3.2 MB
    int*            deg  = (int*)(pos + N_EDGES);                     //  200 KB
    int*            off  = deg + N_NODES;                             //  200 KB

    const int EB = (N_EDGES + 255) / 256;

    convert_v_kernel<<<(N_NODES * DIM / 4 + 255) / 256, 256, 0, stream>>>(v, vb);
    hipMemsetAsync(deg, 0, N_NODES * sizeof(int), stream);
    hist_kernel<<<EB, 256, 0, stream>>>(dst, deg, pos);
    scan_kernel<<<1, SCAN_THREADS, 0, stream>>>(deg, off);
    reorder_kernel<<<EB, 256, 0, stream>>>(e, src, dst, rs, sigma, off, pos, meta);

    // layers: vb -> buf0 -> vb(buf1) -> out
    layer_kernel<<<LAYER_BLOCKS, 256, 0, stream>>>(vb,   v, meta, off, Aw, Ab, buf0, nullptr, 0);
    layer_kernel<<<LAYER_BLOCKS, 256, 0, stream>>>(buf0, v, meta, off, Aw, Ab, vb,   nullptr, 0);
    layer_kernel<<<LAYER_BLOCKS, 256, 0, stream>>>(vb,   v, meta, off, Aw, Ab, nullptr, out,  1);
}

// Round 4
// 398.893 us; speedup vs baseline: 20.9273x; 2.1254x over previous
//
#include <hip/hip_runtime.h>
#include <math.h>

#define N_NODES 50000
#define N_PAD   50048          // rows padded to multiple of 64
#define N_EDGES 1600000
#define DIM     128
#define RCUT    5.0f
#define SCAN_CHUNK 1024
#define SCAN_BLOCKS ((N_NODES + SCAN_CHUNK - 1) / SCAN_CHUNK)   // 49

typedef __attribute__((ext_vector_type(8))) __bf16 bf16x8;
typedef __attribute__((ext_vector_type(4))) float  f32x4;

// ---------------- bf16 helpers ----------------
__device__ __forceinline__ float bf_lo(unsigned int u) { return __uint_as_float(u << 16); }
__device__ __forceinline__ float bf_hi(unsigned int u) { return __uint_as_float(u & 0xffff0000u); }
__device__ __forceinline__ unsigned short f2bf(float x) {
    unsigned int u = __float_as_uint(x);
    u += 0x7fffu + ((u >> 16) & 1u);   // round-to-nearest-even
    return (unsigned short)(u >> 16);
}

// ---------------- v (fp32) -> bf16 ----------------
__global__ void convert_v_kernel(const float* __restrict__ v,
                                 unsigned short* __restrict__ vb) {
    int i = blockIdx.x * blockDim.x + threadIdx.x;   // one float4 -> 4 bf16
    if (i >= N_NODES * DIM / 4) return;
    float4 x = ((const float4*)v)[i];
    uint2 o;
    o.x = (unsigned)f2bf(x.x) | ((unsigned)f2bf(x.y) << 16);
    o.y = (unsigned)f2bf(x.z) | ((unsigned)f2bf(x.w) << 16);
    ((uint2*)vb)[i] = o;
}

// ---------------- W -> MFMA B-operand fragments ----------------
// wfrag[kk][nt][lane] = 8 bf16 of B[k][n], k=kk*32+(lane>>4)*8+i, n=nt*16+(lane&15)
// B[k][n] = At[k][n] = Aw[n][k]
__global__ void wprep_kernel(const float* __restrict__ Aw, uint4* __restrict__ wfrag) {
    int t = blockIdx.x * 256 + threadIdx.x;
    if (t >= 2048) return;
    int lane = t & 63, nt = (t >> 6) & 7, kk = t >> 9;
    int n  = nt * 16 + (lane & 15);
    int k0 = kk * 32 + (lane >> 4) * 8;
    unsigned short h[8];
    #pragma unroll
    for (int i = 0; i < 8; ++i) h[i] = f2bf(Aw[n * DIM + k0 + i]);
    uint4 o;
    o.x = h[0] | ((unsigned)h[1] << 16); o.y = h[2] | ((unsigned)h[3] << 16);
    o.z = h[4] | ((unsigned)h[5] << 16); o.w = h[6] | ((unsigned)h[7] << 16);
    wfrag[t] = o;
}

// ---------------- degree histogram + per-edge slot ----------------
__global__ void hist_kernel(const int* __restrict__ dst,
                            int* __restrict__ deg,
                            unsigned short* __restrict__ pos) {
    int i = blockIdx.x * blockDim.x + threadIdx.x;
    if (i < N_EDGES) pos[i] = (unsigned short)atomicAdd(&deg[dst[i]], 1);
}

// ---------------- 3-phase parallel exclusive scan ----------------
__global__ __launch_bounds__(256) void scanA_kernel(const int* __restrict__ deg,
                                                    int* __restrict__ bsum) {
    __shared__ int red[256];
    int b = blockIdx.x, tid = threadIdx.x;
    int i0 = b * SCAN_CHUNK + tid * 4;
    int s = 0;
    #pragma unroll
    for (int i = 0; i < 4; ++i) { int idx = i0 + i; if (idx < N_NODES) s += deg[idx]; }
    red[tid] = s; __syncthreads();
    for (int d = 128; d > 0; d >>= 1) { if (tid < d) red[tid] += red[tid + d]; __syncthreads(); }
    if (tid == 0) bsum[b] = red[0];
}

__global__ void scanB_kernel(const int* __restrict__ bsum,
                             int* __restrict__ boff,
                             int* __restrict__ off) {
    if (threadIdx.x == 0) {
        int run = 0;
        for (int i = 0; i < SCAN_BLOCKS; ++i) { boff[i] = run; run += bsum[i]; }
        off[N_NODES] = run;
    }
}

__global__ __launch_bounds__(256) void scanC_kernel(const int* __restrict__ deg,
                                                    const int* __restrict__ boff,
                                                    int* __restrict__ off) {
    __shared__ int part[256];
    int b = blockIdx.x, tid = threadIdx.x;
    int i0 = b * SCAN_CHUNK + tid * 4;
    int d0 = (i0 + 0 < N_NODES) ? deg[i0 + 0] : 0;
    int d1 = (i0 + 1 < N_NODES) ? deg[i0 + 1] : 0;
    int d2 = (i0 + 2 < N_NODES) ? deg[i0 + 2] : 0;
    int d3 = (i0 + 3 < N_NODES) ? deg[i0 + 3] : 0;
    part[tid] = d0 + d1 + d2 + d3;
    __syncthreads();
    for (int d = 1; d < 256; d <<= 1) {
        int val = (tid >= d) ? part[tid - d] : 0;
        __syncthreads(); part[tid] += val; __syncthreads();
    }
    int run = boff[b] + ((tid == 0) ? 0 : part[tid - 1]);
    if (i0 + 0 < N_NODES) { off[i0 + 0] = run; run += d0; }
    if (i0 + 1 < N_NODES) { off[i0 + 1] = run; run += d1; }
    if (i0 + 2 < N_NODES) { off[i0 + 2] = run; run += d2; }
    if (i0 + 3 < N_NODES) { off[i0 + 3] = run; run += d3; }
}

// ---------------- reorder (atomic-free) + fused envelope ----------------
__global__ void reorder_kernel(const float* __restrict__ e,
                               const int*   __restrict__ src,
                               const int*   __restrict__ dst,
                               const float* __restrict__ rs,
                               const float* __restrict__ sigma,
                               const int*   __restrict__ off,
                               const unsigned short* __restrict__ pos,
                               int2* __restrict__ meta) {
    int i = blockIdx.x * blockDim.x + threadIdx.x;
    if (i >= N_EDGES) return;
    float r  = e[i];
    float d  = r - rs[0];
    float sg = sigma[0];
    float gauss = expf(-(d * d) / (sg * sg));
    float cut   = 0.5f * cosf(r * (float)(M_PI / (double)RCUT));
    cut = (r < RCUT) ? cut : 0.0f;
    float fe = gauss * cut;
    meta[off[dst[i]] + (int)pos[i]] = make_int2(src[i], __float_as_int(fe));
}

// ---------------- gather: one wave per node, lane owns 2 dims ----------------
// svf[n] = v[n] + sum_e f[e] * cur[src[e]]   (bf16 out)
__global__ __launch_bounds__(256) void gather_kernel(
        const unsigned short* __restrict__ cur,   // bf16 [N_PAD, DIM]
        const float* __restrict__ v,              // fp32 [N, DIM]
        const int2*  __restrict__ meta,
        const int*   __restrict__ off,
        unsigned short* __restrict__ svf) {       // bf16 [N_PAD, DIM]
    int n    = (blockIdx.x << 2) + (threadIdx.x >> 6);
    int lane = threadIdx.x & 63;
    if (n >= N_NODES) return;

    float2 vv = *(const float2*)(v + (size_t)n * DIM + lane * 2);
    float a0 = vv.x, a1 = vv.y;

    int beg = __builtin_amdgcn_readfirstlane(off[n]);
    int end = __builtin_amdgcn_readfirstlane(off[n + 1]);
    const unsigned short* base = cur + lane * 2;

    int c = beg;
    // align c to even so int4 meta loads are 16B-aligned
    if ((c & 1) && c < end) {
        int2 m = meta[c];
        unsigned r = *(const unsigned*)(base + (size_t)m.x * DIM);
        float f = __int_as_float(m.y);
        a0 = fmaf(f, bf_lo(r), a0); a1 = fmaf(f, bf_hi(r), a1);
        ++c;
    }
    for (; c + 8 <= end; c += 8) {
        int4 m0 = *(const int4*)(meta + c);
        int4 m1 = *(const int4*)(meta + c + 2);
        int4 m2 = *(const int4*)(meta + c + 4);
        int4 m3 = *(const int4*)(meta + c + 6);
        unsigned r0 = *(const unsigned*)(base + (size_t)m0.x * DIM);
        unsigned r1 = *(const unsigned*)(base + (size_t)m0.z * DIM);
        unsigned r2 = *(const unsigned*)(base + (size_t)m1.x * DIM);
        unsigned r3 = *(const unsigned*)(base + (size_t)m1.z * DIM);
        unsigned r4 = *(const unsigned*)(base + (size_t)m2.x * DIM);
        unsigned r5 = *(const unsigned*)(base + (size_t)m2.z * DIM);
        unsigned r6 = *(const unsigned*)(base + (size_t)m3.x * DIM);
        unsigned r7 = *(const unsigned*)(base + (size_t)m3.z * DIM);
        float f0 = __int_as_float(m0.y), f1 = __int_as_float(m0.w);
        float f2 = __int_as_float(m1.y), f3 = __int_as_float(m1.w);
        float f4 = __int_as_float(m2.y), f5 = __int_as_float(m2.w);
        float f6 = __int_as_float(m3.y), f7 = __int_as_float(m3.w);
        a0 = fmaf(f0, bf_lo(r0), a0); a1 = fmaf(f0, bf_hi(r0), a1);
        a0 = fmaf(f1, bf_lo(r1), a0); a1 = fmaf(f1, bf_hi(r1), a1);
        a0 = fmaf(f2, bf_lo(r2), a0); a1 = fmaf(f2, bf_hi(r2), a1);
        a0 = fmaf(f3, bf_lo(r3), a0); a1 = fmaf(f3, bf_hi(r3), a1);
        a0 = fmaf(f4, bf_lo(r4), a0); a1 = fmaf(f4, bf_hi(r4), a1);
        a0 = fmaf(f5, bf_lo(r5), a0); a1 = fmaf(f5, bf_hi(r5), a1);
        a0 = fmaf(f6, bf_lo(r6), a0); a1 = fmaf(f6, bf_hi(r6), a1);
        a0 = fmaf(f7, bf_lo(r7), a0); a1 = fmaf(f7, bf_hi(r7), a1);
    }
    for (; c < end; ++c) {
        int2 m = meta[c];
        unsigned r = *(const unsigned*)(base + (size_t)m.x * DIM);
        float f = __int_as_float(m.y);
        a0 = fmaf(f, bf_lo(r), a0); a1 = fmaf(f, bf_hi(r), a1);
    }
    unsigned o = (unsigned)f2bf(a0) | ((unsigned)f2bf(a1) << 16);
    *(unsigned*)(svf + (size_t)n * DIM + lane * 2) = o;
}

// ---------------- GEMM+bias+ReLU via MFMA ----------------
// out = relu(X @ At + b). Block = 4 waves = 64 rows; wave = 16 rows x 128 cols.
__global__ __launch_bounds__(256) void gemm_kernel(
        const unsigned short* __restrict__ X,     // bf16 [N_PAD, DIM]
        const uint4* __restrict__ wfrag,          // [4][8][64] fragments
        const float* __restrict__ bias,
        unsigned short* __restrict__ out_bf,
        float* __restrict__ out_f,
        int last) {
    __shared__ uint4 wlds[2048];                  // 32 KB
    int tid = threadIdx.x;
    for (int i = tid; i < 2048; i += 256) wlds[i] = wfrag[i];

    int wv = tid >> 6, lane = tid & 63;
    int quad = lane >> 4, l16 = lane & 15;
    int row = blockIdx.x * 64 + wv * 16 + l16;

    f32x4 acc[8];
    #pragma unroll
    for (int i = 0; i < 8; ++i) acc[i] = (f32x4){0.f, 0.f, 0.f, 0.f};

    __syncthreads();

    const unsigned short* xp = X + (size_t)row * DIM + quad * 8;
    #pragma unroll
    for (int kk = 0; kk < 4; ++kk) {
        bf16x8 af = *(const bf16x8*)(xp + kk * 32);
        #pragma unroll
        for (int nt = 0; nt < 8; ++nt) {
            uint4 w = wlds[(kk * 8 + nt) * 64 + lane];
            bf16x8 bfr = __builtin_bit_cast(bf16x8, w);
            acc[nt] = __builtin_amdgcn_mfma_f32_16x16x32_bf16(af, bfr, acc[nt], 0, 0, 0);
        }
    }

    int orow0 = blockIdx.x * 64 + wv * 16 + quad * 4;
    #pragma unroll
    for (int nt = 0; nt < 8; ++nt) {
        int col = nt * 16 + l16;
        float b = bias[col];
        #pragma unroll
        for (int r = 0; r < 4; ++r) {
            int orow = orow0 + r;
            if (orow < N_NODES) {
                float val = fmaxf(acc[nt][r] + b, 0.f);
                if (last) out_f[(size_t)orow * DIM + col] = val;
                else      out_bf[(size_t)orow * DIM + col] = f2bf(val);
            }
        }
    }
}

// ---------------------------------------------------------------------------
extern "C" void kernel_launch(void* const* d_in, const int* in_sizes, int n_in,
                              void* d_out, int out_size, void* d_ws, size_t ws_size,
                              hipStream_t stream) {
    const float* v     = (const float*)d_in[0];
    const float* e     = (const float*)d_in[1];
    const int*   src   = (const int*)  d_in[2];
    const int*   dst   = (const int*)  d_in[3];
    const float* Aw    = (const float*)d_in[4];
    const float* Ab    = (const float*)d_in[5];
    const float* rs    = (const float*)d_in[6];
    const float* sigma = (const float*)d_in[7];
    float* out = (float*)d_out;

    // ---- workspace layout (~54.9 MB; 57.6 MB proven available) ----
    char* p = (char*)d_ws;
    int2*           meta  = (int2*)p;            p += (size_t)N_EDGES * 8;       // 12.8 MB
    unsigned short* bufV  = (unsigned short*)p;  p += (size_t)N_PAD * DIM * 2;   // 12.81 MB
    unsigned short* bufA  = (unsigned short*)p;  p += (size_t)N_PAD * DIM * 2;   // 12.81 MB
    unsigned short* bufB  = (unsigned short*)p;  p += (size_t)N_PAD * DIM * 2;   // 12.81 MB
    unsigned short* pos   = (unsigned short*)p;  p += (size_t)N_EDGES * 2;       //  3.2 MB
    uint4*          wfrag = (uint4*)p;           p += 2048 * 16;                 //  32 KB
    int*            deg   = (int*)p;             p += (size_t)N_NODES * 4;
    int*            off   = (int*)p;             p += (size_t)(N_NODES + 1) * 4;
    int*            bsum  = (int*)p;             p += 64 * 4;
    int*            boff  = (int*)p;

    const int EB = (N_EDGES + 255) / 256;

    convert_v_kernel<<<(N_NODES * DIM / 4 + 255) / 256, 256, 0, stream>>>(v, bufV);
    wprep_kernel<<<8, 256, 0, stream>>>(Aw, wfrag);
    hipMemsetAsync(deg, 0, N_NODES * sizeof(int), stream);
    hist_kernel<<<EB, 256, 0, stream>>>(dst, deg, pos);
    scanA_kernel<<<SCAN_BLOCKS, 256, 0, stream>>>(deg, bsum);
    scanB_kernel<<<1, 64, 0, stream>>>(bsum, boff, off);
    scanC_kernel<<<SCAN_BLOCKS, 256, 0, stream>>>(deg, boff, off);
    reorder_kernel<<<EB, 256, 0, stream>>>(e, src, dst, rs, sigma, off, pos, meta);

    const int GB = (N_NODES + 3) / 4;     // 12500 blocks (4 waves each)
    const int MB = N_PAD / 64;            // 782 blocks

    // L0: bufV -> bufA -> bufB ; L1: bufB -> bufA -> bufV ; L2: bufV -> bufA -> out
    gather_kernel<<<GB, 256, 0, stream>>>(bufV, v, meta, off, bufA);
    gemm_kernel<<<MB, 256, 0, stream>>>(bufA, wfrag, Ab, bufB, nullptr, 0);
    gather_kernel<<<GB, 256, 0, stream>>>(bufB, v, meta, off, bufA);
    gemm_kernel<<<MB, 256, 0, stream>>>(bufA, wfrag, Ab, bufV, nullptr, 0);
    gather_kernel<<<GB, 256, 0, stream>>>(bufV, v, meta, off, bufA);
    gemm_kernel<<<MB, 256, 0, stream>>>(bufA, wfrag, Ab, nullptr, out, 1);
}

// Round 5
// 398.635 us; speedup vs baseline: 20.9408x; 1.0006x over previous
//
#include <hip/hip_runtime.h>
#include <math.h>

#define N_NODES 50000
#define N_PAD   50048          // rows padded to multiple of 64
#define N_EDGES 1600000
#define DIM     128
#define RCUT    5.0f
#define NSHARD  8
#define SCAN_CHUNK 1024
#define SCAN_BLOCKS ((N_NODES + SCAN_CHUNK - 1) / SCAN_CHUNK)   // 49

typedef __attribute__((ext_vector_type(8))) __bf16 bf16x8;
typedef __attribute__((ext_vector_type(4))) float  f32x4;

// ---------------- bf16 helpers ----------------
__device__ __forceinline__ float bf_lo(unsigned int u) { return __uint_as_float(u << 16); }
__device__ __forceinline__ float bf_hi(unsigned int u) { return __uint_as_float(u & 0xffff0000u); }
__device__ __forceinline__ unsigned short f2bf(float x) {
    unsigned int u = __float_as_uint(x);
    u += 0x7fffu + ((u >> 16) & 1u);   // round-to-nearest-even
    return (unsigned short)(u >> 16);
}

// ---------------- v (fp32) -> bf16 ----------------
__global__ void convert_v_kernel(const float* __restrict__ v,
                                 unsigned short* __restrict__ vb) {
    int i = blockIdx.x * blockDim.x + threadIdx.x;   // one float4 -> 4 bf16
    if (i >= N_NODES * DIM / 4) return;
    float4 x = ((const float4*)v)[i];
    uint2 o;
    o.x = (unsigned)f2bf(x.x) | ((unsigned)f2bf(x.y) << 16);
    o.y = (unsigned)f2bf(x.z) | ((unsigned)f2bf(x.w) << 16);
    ((uint2*)vb)[i] = o;
}

// ---------------- W -> MFMA B-operand fragments ----------------
__global__ void wprep_kernel(const float* __restrict__ Aw, uint4* __restrict__ wfrag) {
    int t = blockIdx.x * 256 + threadIdx.x;
    if (t >= 2048) return;
    int lane = t & 63, nt = (t >> 6) & 7, kk = t >> 9;
    int n  = nt * 16 + (lane & 15);
    int k0 = kk * 32 + (lane >> 4) * 8;
    unsigned short h[8];
    #pragma unroll
    for (int i = 0; i < 8; ++i) h[i] = f2bf(Aw[n * DIM + k0 + i]);
    uint4 o;
    o.x = h[0] | ((unsigned)h[1] << 16); o.y = h[2] | ((unsigned)h[3] << 16);
    o.z = h[4] | ((unsigned)h[5] << 16); o.w = h[6] | ((unsigned)h[7] << 16);
    wfrag[t] = o;
}

// ---------------- sharded degree histogram + per-edge slot ----------------
__global__ void hist_kernel(const int* __restrict__ dst,
                            int* __restrict__ deg8,
                            unsigned short* __restrict__ pos) {
    int i = blockIdx.x * blockDim.x + threadIdx.x;
    if (i >= N_EDGES) return;
    int s = (i >> 6) & (NSHARD - 1);
    pos[i] = (unsigned short)atomicAdd(&deg8[s * N_NODES + dst[i]], 1);
}

// ---------------- 3-phase parallel exclusive scan over shard-summed deg ----
__global__ __launch_bounds__(256) void scanA_kernel(const int* __restrict__ deg8,
                                                    int* __restrict__ bsum) {
    __shared__ int red[256];
    int b = blockIdx.x, tid = threadIdx.x;
    int i0 = b * SCAN_CHUNK + tid * 4;
    int s = 0;
    #pragma unroll
    for (int r = 0; r < 4; ++r) {
        int idx = i0 + r;
        if (idx < N_NODES)
            #pragma unroll
            for (int sh = 0; sh < NSHARD; ++sh) s += deg8[sh * N_NODES + idx];
    }
    red[tid] = s; __syncthreads();
    for (int d = 128; d > 0; d >>= 1) { if (tid < d) red[tid] += red[tid + d]; __syncthreads(); }
    if (tid == 0) bsum[b] = red[0];
}

__global__ void scanB_kernel(const int* __restrict__ bsum,
                             int* __restrict__ boff,
                             int* __restrict__ off) {
    if (threadIdx.x == 0) {
        int run = 0;
        for (int i = 0; i < SCAN_BLOCKS; ++i) { boff[i] = run; run += bsum[i]; }
        off[N_NODES] = run;
    }
}

__global__ __launch_bounds__(256) void scanC_kernel(const int* __restrict__ deg8,
                                                    const int* __restrict__ boff,
                                                    int* __restrict__ off,
                                                    int* __restrict__ off2) {
    __shared__ int part[256];
    int b = blockIdx.x, tid = threadIdx.x;
    int i0 = b * SCAN_CHUNK + tid * 4;
    int dsh[4][NSHARD];
    int tot[4];
    #pragma unroll
    for (int r = 0; r < 4; ++r) {
        int idx = i0 + r;
        tot[r] = 0;
        #pragma unroll
        for (int sh = 0; sh < NSHARD; ++sh) {
            int val = (idx < N_NODES) ? deg8[sh * N_NODES + idx] : 0;
            dsh[r][sh] = val; tot[r] += val;
        }
    }
    part[tid] = tot[0] + tot[1] + tot[2] + tot[3];
    __syncthreads();
    for (int d = 1; d < 256; d <<= 1) {
        int val = (tid >= d) ? part[tid - d] : 0;
        __syncthreads(); part[tid] += val; __syncthreads();
    }
    int run = boff[b] + ((tid == 0) ? 0 : part[tid - 1]);
    #pragma unroll
    for (int r = 0; r < 4; ++r) {
        int idx = i0 + r;
        if (idx < N_NODES) {
            off[idx] = run;
            int rs = run;
            #pragma unroll
            for (int sh = 0; sh < NSHARD; ++sh) {
                off2[sh * N_NODES + idx] = rs; rs += dsh[r][sh];
            }
            run += tot[r];
        }
    }
}

// ---------------- reorder (atomic-free) + fused envelope ----------------
// meta[pos] = { src byte-offset (src*DIM*2), bitcast(f) }
__global__ void reorder_kernel(const float* __restrict__ e,
                               const int*   __restrict__ src,
                               const int*   __restrict__ dst,
                               const float* __restrict__ rs,
                               const float* __restrict__ sigma,
                               const int*   __restrict__ off2,
                               const unsigned short* __restrict__ pos,
                               int2* __restrict__ meta) {
    int i = blockIdx.x * blockDim.x + threadIdx.x;
    if (i >= N_EDGES) return;
    float r  = e[i];
    float d  = r - rs[0];
    float sg = sigma[0];
    float gauss = expf(-(d * d) / (sg * sg));
    float cut   = 0.5f * cosf(r * (float)(M_PI / (double)RCUT));
    cut = (r < RCUT) ? cut : 0.0f;
    float fe = gauss * cut;
    int s = (i >> 6) & (NSHARD - 1);
    int p = off2[s * N_NODES + dst[i]] + (int)pos[i];
    meta[p] = make_int2(src[i] * (DIM * 2), __float_as_int(fe));
}

// ---------------- gather: one wave per node, lane owns 2 dims ----------------
// svf[n] = v[n] + sum_e f[e] * cur[src[e]]   (bf16 out)
__global__ __launch_bounds__(256) void gather_kernel(
        const unsigned short* __restrict__ cur,   // bf16 [N_PAD, DIM]
        const float* __restrict__ v,              // fp32 [N, DIM]
        const int2*  __restrict__ meta,
        const int*   __restrict__ off,
        unsigned short* __restrict__ svf) {       // bf16 [N_PAD, DIM]
    int n    = (blockIdx.x << 2) + (threadIdx.x >> 6);
    int lane = threadIdx.x & 63;
    if (n >= N_NODES) return;

    float2 vv = *(const float2*)(v + (size_t)n * DIM + lane * 2);
    float a0 = vv.x, a1 = vv.y;

    int beg = __builtin_amdgcn_readfirstlane(off[n]);
    int end = __builtin_amdgcn_readfirstlane(off[n + 1]);
    const char* base = (const char*)cur + lane * 4;

    int c = beg;
    if ((c & 1) && c < end) {
        int2 m = meta[c];
        unsigned r = *(const unsigned*)(base + (unsigned)m.x);
        float f = __int_as_float(m.y);
        a0 = fmaf(f, bf_lo(r), a0); a1 = fmaf(f, bf_hi(r), a1);
        ++c;
    }
    for (; c + 8 <= end; c += 8) {
        int4 m0 = *(const int4*)(meta + c);
        int4 m1 = *(const int4*)(meta + c + 2);
        int4 m2 = *(const int4*)(meta + c + 4);
        int4 m3 = *(const int4*)(meta + c + 6);
        unsigned r0 = *(const unsigned*)(base + (unsigned)m0.x);
        unsigned r1 = *(const unsigned*)(base + (unsigned)m0.z);
        unsigned r2 = *(const unsigned*)(base + (unsigned)m1.x);
        unsigned r3 = *(const unsigned*)(base + (unsigned)m1.z);
        unsigned r4 = *(const unsigned*)(base + (unsigned)m2.x);
        unsigned r5 = *(const unsigned*)(base + (unsigned)m2.z);
        unsigned r6 = *(const unsigned*)(base + (unsigned)m3.x);
        unsigned r7 = *(const unsigned*)(base + (unsigned)m3.z);
        float f0 = __int_as_float(m0.y), f1 = __int_as_float(m0.w);
        float f2 = __int_as_float(m1.y), f3 = __int_as_float(m1.w);
        float f4 = __int_as_float(m2.y), f5 = __int_as_float(m2.w);
        float f6 = __int_as_float(m3.y), f7 = __int_as_float(m3.w);
        a0 = fmaf(f0, bf_lo(r0), a0); a1 = fmaf(f0, bf_hi(r0), a1);
        a0 = fmaf(f1, bf_lo(r1), a0); a1 = fmaf(f1, bf_hi(r1), a1);
        a0 = fmaf(f2, bf_lo(r2), a0); a1 = fmaf(f2, bf_hi(r2), a1);
        a0 = fmaf(f3, bf_lo(r3), a0); a1 = fmaf(f3, bf_hi(r3), a1);
        a0 = fmaf(f4, bf_lo(r4), a0); a1 = fmaf(f4, bf_hi(r4), a1);
        a0 = fmaf(f5, bf_lo(r5), a0); a1 = fmaf(f5, bf_hi(r5), a1);
        a0 = fmaf(f6, bf_lo(r6), a0); a1 = fmaf(f6, bf_hi(r6), a1);
        a0 = fmaf(f7, bf_lo(r7), a0); a1 = fmaf(f7, bf_hi(r7), a1);
    }
    for (; c < end; ++c) {
        int2 m = meta[c];
        unsigned r = *(const unsigned*)(base + (unsigned)m.x);
        float f = __int_as_float(m.y);
        a0 = fmaf(f, bf_lo(r), a0); a1 = fmaf(f, bf_hi(r), a1);
    }
    unsigned o = (unsigned)f2bf(a0) | ((unsigned)f2bf(a1) << 16);
    *(unsigned*)(svf + (size_t)n * DIM + lane * 2) = o;
}

// ---------------- GEMM+bias+ReLU via MFMA ----------------
__global__ __launch_bounds__(256) void gemm_kernel(
        const unsigned short* __restrict__ X,     // bf16 [N_PAD, DIM]
        const uint4* __restrict__ wfrag,          // [4][8][64] fragments
        const float* __restrict__ bias,
        unsigned short* __restrict__ out_bf,
        float* __restrict__ out_f,
        int last) {
    __shared__ uint4 wlds[2048];                  // 32 KB
    int tid = threadIdx.x;
    for (int i = tid; i < 2048; i += 256) wlds[i] = wfrag[i];

    int wv = tid >> 6, lane = tid & 63;
    int quad = lane >> 4, l16 = lane & 15;
    int row = blockIdx.x * 64 + wv * 16 + l16;

    f32x4 acc[8];
    #pragma unroll
    for (int i = 0; i < 8; ++i) acc[i] = (f32x4){0.f, 0.f, 0.f, 0.f};

    __syncthreads();

    const unsigned short* xp = X + (size_t)row * DIM + quad * 8;
    #pragma unroll
    for (int kk = 0; kk < 4; ++kk) {
        bf16x8 af = *(const bf16x8*)(xp + kk * 32);
        #pragma unroll
        for (int nt = 0; nt < 8; ++nt) {
            uint4 w = wlds[(kk * 8 + nt) * 64 + lane];
            bf16x8 bfr = __builtin_bit_cast(bf16x8, w);
            acc[nt] = __builtin_amdgcn_mfma_f32_16x16x32_bf16(af, bfr, acc[nt], 0, 0, 0);
        }
    }

    int orow0 = blockIdx.x * 64 + wv * 16 + quad * 4;
    #pragma unroll
    for (int nt = 0; nt < 8; ++nt) {
        int col = nt * 16 + l16;
        float b = bias[col];
        #pragma unroll
        for (int r = 0; r < 4; ++r) {
            int orow = orow0 + r;
            if (orow < N_NODES) {
                float val = fmaxf(acc[nt][r] + b, 0.f);
                if (last) out_f[(size_t)orow * DIM + col] = val;
                else      out_bf[(size_t)orow * DIM + col] = f2bf(val);
            }
        }
    }
}

// ---------------------------------------------------------------------------
extern "C" void kernel_launch(void* const* d_in, const int* in_sizes, int n_in,
                              void* d_out, int out_size, void* d_ws, size_t ws_size,
                              hipStream_t stream) {
    const float* v     = (const float*)d_in[0];
    const float* e     = (const float*)d_in[1];
    const int*   src   = (const int*)  d_in[2];
    const int*   dst   = (const int*)  d_in[3];
    const float* Aw    = (const float*)d_in[4];
    const float* Ab    = (const float*)d_in[5];
    const float* rs    = (const float*)d_in[6];
    const float* sigma = (const float*)d_in[7];
    float* out = (float*)d_out;

    // ---- workspace layout (~51.5 MB) ----
    char* p = (char*)d_ws;
    int2*           meta  = (int2*)p;            p += (size_t)N_EDGES * 8;       // 12.8 MB
    unsigned short* bufV  = (unsigned short*)p;  p += (size_t)N_PAD * DIM * 2;   // 12.81 MB
    unsigned short* bufA  = (unsigned short*)p;  p += (size_t)N_PAD * DIM * 2;   // 12.81 MB
    unsigned short* bufB  = (unsigned short*)p;  p += (size_t)N_PAD * DIM * 2;   // 12.81 MB
    uint4*          wfrag = (uint4*)p;           p += 2048 * 16;                 //  32 KB
    int*            off   = (int*)p;             p += (size_t)(N_NODES + 1) * 4;
    int*            bsum  = (int*)p;             p += 64 * 4;
    int*            boff  = (int*)p;             p += 64 * 4;
    // aliases: dead before host buffer first written
    int*            deg8  = (int*)bufA;                         // 1.6 MB, dead after scanC
    unsigned short* pos   = (unsigned short*)bufB;              // 3.2 MB, dead after reorder
    int*            off2  = (int*)((char*)bufB + (size_t)N_EDGES * 2);  // 1.6 MB, dead after reorder

    const int EB = (N_EDGES + 255) / 256;

    convert_v_kernel<<<(N_NODES * DIM / 4 + 255) / 256, 256, 0, stream>>>(v, bufV);
    wprep_kernel<<<8, 256, 0, stream>>>(Aw, wfrag);
    hipMemsetAsync(deg8, 0, (size_t)NSHARD * N_NODES * sizeof(int), stream);
    hist_kernel<<<EB, 256, 0, stream>>>(dst, deg8, pos);
    scanA_kernel<<<SCAN_BLOCKS, 256, 0, stream>>>(deg8, bsum);
    scanB_kernel<<<1, 64, 0, stream>>>(bsum, boff, off);
    scanC_kernel<<<SCAN_BLOCKS, 256, 0, stream>>>(deg8, boff, off, off2);
    reorder_kernel<<<EB, 256, 0, stream>>>(e, src, dst, rs, sigma, off2, pos, meta);

    const int GB = (N_NODES + 3) / 4;     // 12500 blocks (4 waves each)
    const int MB = N_PAD / 64;            // 782 blocks

    // L0: bufV -> bufA -> bufB ; L1: bufB -> bufA -> bufV ; L2: bufV -> bufA -> out
    gather_kernel<<<GB, 256, 0, stream>>>(bufV, v, meta, off, bufA);
    gemm_kernel<<<MB, 256, 0, stream>>>(bufA, wfrag, Ab, bufB, nullptr, 0);
    gather_kernel<<<GB, 256, 0, stream>>>(bufB, v, meta, off, bufA);
    gemm_kernel<<<MB, 256, 0, stream>>>(bufA, wfrag, Ab, bufV, nullptr, 0);
    gather_kernel<<<GB, 256, 0, stream>>>(bufV, v, meta, off, bufA);
    gemm_kernel<<<MB, 256, 0, stream>>>(bufA, wfrag, Ab, nullptr, out, 1);
}

// Round 6
// 365.432 us; speedup vs baseline: 22.8435x; 1.0909x over previous
//
#include <hip/hip_runtime.h>
#include <math.h>

#define N_NODES 50000
#define N_PAD   50048          // rows padded to multiple of 64
#define N_EDGES 1600000
#define DIM     128
#define RCUT    5.0f
#define NGROUP  (N_PAD / 64)   // 782 groups of 64 nodes
#define NB_PRE  512
#define CH_PRE  (N_EDGES / NB_PRE)   // 3125 edges per preprocessing block

typedef __attribute__((ext_vector_type(8))) __bf16 bf16x8;
typedef __attribute__((ext_vector_type(4))) float  f32x4;

// ---------------- bf16 helpers ----------------
__device__ __forceinline__ float bf_lo(unsigned int u) { return __uint_as_float(u << 16); }
__device__ __forceinline__ float bf_hi(unsigned int u) { return __uint_as_float(u & 0xffff0000u); }
__device__ __forceinline__ unsigned short f2bf(float x) {
    unsigned int u = __float_as_uint(x);
    u += 0x7fffu + ((u >> 16) & 1u);   // round-to-nearest-even
    return (unsigned short)(u >> 16);
}

// ---------------- v (fp32) -> bf16 ----------------
__global__ void convert_v_kernel(const float* __restrict__ v,
                                 unsigned short* __restrict__ vb) {
    int i = blockIdx.x * blockDim.x + threadIdx.x;   // one float4 -> 4 bf16
    if (i >= N_NODES * DIM / 4) return;
    float4 x = ((const float4*)v)[i];
    uint2 o;
    o.x = (unsigned)f2bf(x.x) | ((unsigned)f2bf(x.y) << 16);
    o.y = (unsigned)f2bf(x.z) | ((unsigned)f2bf(x.w) << 16);
    ((uint2*)vb)[i] = o;
}

// ---------------- W -> MFMA B-operand fragments ----------------
__global__ void wprep_kernel(const float* __restrict__ Aw, uint4* __restrict__ wfrag) {
    int t = blockIdx.x * 256 + threadIdx.x;
    if (t >= 2048) return;
    int lane = t & 63, nt = (t >> 6) & 7, kk = t >> 9;
    int n  = nt * 16 + (lane & 15);
    int k0 = kk * 32 + (lane >> 4) * 8;
    unsigned short h[8];
    #pragma unroll
    for (int i = 0; i < 8; ++i) h[i] = f2bf(Aw[n * DIM + k0 + i]);
    uint4 o;
    o.x = h[0] | ((unsigned)h[1] << 16); o.y = h[2] | ((unsigned)h[3] << 16);
    o.z = h[4] | ((unsigned)h[5] << 16); o.w = h[6] | ((unsigned)h[7] << 16);
    wfrag[t] = o;
}

// ---------------- per-block group histogram (LDS only, no global atomics) ----
__global__ __launch_bounds__(256) void countp_kernel(const int* __restrict__ dst,
                                                     int* __restrict__ partial) {
    __shared__ int h[NGROUP];
    int b = blockIdx.x, tid = threadIdx.x;
    for (int g = tid; g < NGROUP; g += 256) h[g] = 0;
    __syncthreads();
    int beg = b * CH_PRE, end = beg + CH_PRE;
    for (int i = beg + tid; i < end; i += 256)
        atomicAdd(&h[dst[i] >> 6], 1);                 // LDS atomic
    __syncthreads();
    for (int g = tid; g < NGROUP; g += 256) partial[b * NGROUP + g] = h[g];
}

// ---------------- group totals ----------------
__global__ __launch_bounds__(256) void sumA_kernel(const int* __restrict__ partial,
                                                   int* __restrict__ gtot) {
    __shared__ int red[256];
    int g = blockIdx.x, tid = threadIdx.x;
    int s = partial[tid * NGROUP + g] + partial[(tid + 256) * NGROUP + g];
    red[tid] = s; __syncthreads();
    for (int d = 128; d > 0; d >>= 1) { if (tid < d) red[tid] += red[tid + d]; __syncthreads(); }
    if (tid == 0) gtot[g] = red[0];
}

// ---------------- exclusive scan over 782 group totals ----------------
__global__ __launch_bounds__(256) void scanB_kernel(const int* __restrict__ gtot,
                                                    int* __restrict__ goff) {
    __shared__ int part[256];
    int tid = threadIdx.x;
    int i0 = tid * 4;
    int v[4]; int s = 0;
    #pragma unroll
    for (int k = 0; k < 4; ++k) { int i = i0 + k; v[k] = (i < NGROUP) ? gtot[i] : 0; s += v[k]; }
    part[tid] = s; __syncthreads();
    for (int d = 1; d < 256; d <<= 1) {
        int val = (tid >= d) ? part[tid - d] : 0;
        __syncthreads(); part[tid] += val; __syncthreads();
    }
    int run = (tid == 0) ? 0 : part[tid - 1];
    #pragma unroll
    for (int k = 0; k < 4; ++k) {
        int i = i0 + k;
        if (i < NGROUP) { goff[i] = run; run += v[k]; }
    }
    if (tid == 0) goff[NGROUP] = N_EDGES;
}

// ---------------- per-(block,group) bases ----------------
__global__ __launch_bounds__(256) void scanC_kernel(const int* __restrict__ partial,
                                                    const int* __restrict__ goff,
                                                    int* __restrict__ pbase) {
    __shared__ int part[256];
    int g = blockIdx.x, tid = threadIdx.x;
    int v0 = partial[(2 * tid) * NGROUP + g];
    int v1 = partial[(2 * tid + 1) * NGROUP + g];
    part[tid] = v0 + v1; __syncthreads();
    for (int d = 1; d < 256; d <<= 1) {
        int val = (tid >= d) ? part[tid - d] : 0;
        __syncthreads(); part[tid] += val; __syncthreads();
    }
    int run = goff[g] + ((tid == 0) ? 0 : part[tid - 1]);
    pbase[(2 * tid) * NGROUP + g] = run;
    pbase[(2 * tid + 1) * NGROUP + g] = run + v0;
}

// ---------------- reorder into group-CSR (LDS rank, no global atomics) -----
// metaT[slot] = { src*256 | tag<<24, bitcast(f) },  tag = dst & 63
__global__ __launch_bounds__(256) void reorder_kernel(
        const float* __restrict__ e,
        const int*   __restrict__ src,
        const int*   __restrict__ dst,
        const float* __restrict__ rs,
        const float* __restrict__ sigma,
        const int*   __restrict__ pbase,
        int2* __restrict__ metaT) {
    __shared__ int base[NGROUP];
    __shared__ int cnt[NGROUP];
    int b = blockIdx.x, tid = threadIdx.x;
    for (int g = tid; g < NGROUP; g += 256) { base[g] = pbase[b * NGROUP + g]; cnt[g] = 0; }
    __syncthreads();
    float rsv = rs[0], sg = sigma[0];
    int beg = b * CH_PRE, end = beg + CH_PRE;
    for (int i = beg + tid; i < end; i += 256) {
        float r  = e[i];
        float d  = r - rsv;
        float gauss = expf(-(d * d) / (sg * sg));
        float cut   = 0.5f * cosf(r * (float)(M_PI / (double)RCUT));
        cut = (r < RCUT) ? cut : 0.0f;
        float fe = gauss * cut;
        int dn  = dst[i];
        int g   = dn >> 6;
        int lr  = atomicAdd(&cnt[g], 1);               // LDS atomic
        int slot = base[g] + lr;
        metaT[slot] = make_int2(src[i] * (DIM * 2) | ((dn & 63) << 24),
                                __float_as_int(fe));
    }
}

// ---------------- 64-bin counting sort per group -> node-exact CSR ---------
__global__ __launch_bounds__(256) void tagsort_kernel(
        const int2* __restrict__ metaT,
        const int*  __restrict__ goff,
        int2* __restrict__ meta,
        int*  __restrict__ off) {
    __shared__ int cnt[64], base[64], cur[64];
    int g = blockIdx.x, tid = threadIdx.x;
    int sbeg = goff[g], send = goff[g + 1];
    if (tid < 64) cnt[tid] = 0;
    __syncthreads();
    for (int i = sbeg + tid; i < send; i += 256)
        atomicAdd(&cnt[(metaT[i].x >> 24) & 63], 1);   // LDS atomic
    __syncthreads();
    if (tid == 0) {
        int run = 0;
        #pragma unroll
        for (int t = 0; t < 64; ++t) { base[t] = run; cur[t] = run; run += cnt[t]; }
    }
    __syncthreads();
    if (tid < 64) {
        int node = g * 64 + tid;
        if (node <= N_NODES) off[node] = sbeg + base[tid];
    }
    __syncthreads();
    for (int i = sbeg + tid; i < send; i += 256) {
        int2 m = metaT[i];
        int tag = (m.x >> 24) & 63;
        int lr = atomicAdd(&cur[tag], 1);              // LDS atomic
        meta[sbeg + lr] = make_int2(m.x & 0x00FFFFFF, m.y);
    }
}

// ---------------- gather: one wave per node, lane owns 2 dims ----------------
__global__ __launch_bounds__(256) void gather_kernel(
        const unsigned short* __restrict__ cur,   // bf16 [N_PAD, DIM]
        const float* __restrict__ v,              // fp32 [N, DIM]
        const int2*  __restrict__ meta,
        const int*   __restrict__ off,
        unsigned short* __restrict__ svf) {       // bf16 [N_PAD, DIM]
    int n    = (blockIdx.x << 2) + (threadIdx.x >> 6);
    int lane = threadIdx.x & 63;
    if (n >= N_NODES) return;

    float2 vv = *(const float2*)(v + (size_t)n * DIM + lane * 2);
    float a0 = vv.x, a1 = vv.y;

    int beg = __builtin_amdgcn_readfirstlane(off[n]);
    int end = __builtin_amdgcn_readfirstlane(off[n + 1]);
    const char* base = (const char*)cur + lane * 4;

    int c = beg;
    if ((c & 1) && c < end) {
        int2 m = meta[c];
        unsigned r = *(const unsigned*)(base + (unsigned)m.x);
        float f = __int_as_float(m.y);
        a0 = fmaf(f, bf_lo(r), a0); a1 = fmaf(f, bf_hi(r), a1);
        ++c;
    }
    for (; c + 8 <= end; c += 8) {
        int4 m0 = *(const int4*)(meta + c);
        int4 m1 = *(const int4*)(meta + c + 2);
        int4 m2 = *(const int4*)(meta + c + 4);
        int4 m3 = *(const int4*)(meta + c + 6);
        unsigned r0 = *(const unsigned*)(base + (unsigned)m0.x);
        unsigned r1 = *(const unsigned*)(base + (unsigned)m0.z);
        unsigned r2 = *(const unsigned*)(base + (unsigned)m1.x);
        unsigned r3 = *(const unsigned*)(base + (unsigned)m1.z);
        unsigned r4 = *(const unsigned*)(base + (unsigned)m2.x);
        unsigned r5 = *(const unsigned*)(base + (unsigned)m2.z);
        unsigned r6 = *(const unsigned*)(base + (unsigned)m3.x);
        unsigned r7 = *(const unsigned*)(base + (unsigned)m3.z);
        float f0 = __int_as_float(m0.y), f1 = __int_as_float(m0.w);
        float f2 = __int_as_float(m1.y), f3 = __int_as_float(m1.w);
        float f4 = __int_as_float(m2.y), f5 = __int_as_float(m2.w);
        float f6 = __int_as_float(m3.y), f7 = __int_as_float(m3.w);
        a0 = fmaf(f0, bf_lo(r0), a0); a1 = fmaf(f0, bf_hi(r0), a1);
        a0 = fmaf(f1, bf_lo(r1), a0); a1 = fmaf(f1, bf_hi(r1), a1);
        a0 = fmaf(f2, bf_lo(r2), a0); a1 = fmaf(f2, bf_hi(r2), a1);
        a0 = fmaf(f3, bf_lo(r3), a0); a1 = fmaf(f3, bf_hi(r3), a1);
        a0 = fmaf(f4, bf_lo(r4), a0); a1 = fmaf(f4, bf_hi(r4), a1);
        a0 = fmaf(f5, bf_lo(r5), a0); a1 = fmaf(f5, bf_hi(r5), a1);
        a0 = fmaf(f6, bf_lo(r6), a0); a1 = fmaf(f6, bf_hi(r6), a1);
        a0 = fmaf(f7, bf_lo(r7), a0); a1 = fmaf(f7, bf_hi(r7), a1);
    }
    for (; c < end; ++c) {
        int2 m = meta[c];
        unsigned r = *(const unsigned*)(base + (unsigned)m.x);
        float f = __int_as_float(m.y);
        a0 = fmaf(f, bf_lo(r), a0); a1 = fmaf(f, bf_hi(r), a1);
    }
    unsigned o = (unsigned)f2bf(a0) | ((unsigned)f2bf(a1) << 16);
    *(unsigned*)(svf + (size_t)n * DIM + lane * 2) = o;
}

// ---------------- GEMM+bias+ReLU via MFMA ----------------
__global__ __launch_bounds__(256) void gemm_kernel(
        const unsigned short* __restrict__ X,     // bf16 [N_PAD, DIM]
        const uint4* __restrict__ wfrag,          // [4][8][64] fragments
        const float* __restrict__ bias,
        unsigned short* __restrict__ out_bf,
        float* __restrict__ out_f,
        int last) {
    __shared__ uint4 wlds[2048];                  // 32 KB
    int tid = threadIdx.x;
    for (int i = tid; i < 2048; i += 256) wlds[i] = wfrag[i];

    int wv = tid >> 6, lane = tid & 63;
    int quad = lane >> 4, l16 = lane & 15;
    int row = blockIdx.x * 64 + wv * 16 + l16;

    f32x4 acc[8];
    #pragma unroll
    for (int i = 0; i < 8; ++i) acc[i] = (f32x4){0.f, 0.f, 0.f, 0.f};

    __syncthreads();

    const unsigned short* xp = X + (size_t)row * DIM + quad * 8;
    #pragma unroll
    for (int kk = 0; kk < 4; ++kk) {
        bf16x8 af = *(const bf16x8*)(xp + kk * 32);
        #pragma unroll
        for (int nt = 0; nt < 8; ++nt) {
            uint4 w = wlds[(kk * 8 + nt) * 64 + lane];
            bf16x8 bfr = __builtin_bit_cast(bf16x8, w);
            acc[nt] = __builtin_amdgcn_mfma_f32_16x16x32_bf16(af, bfr, acc[nt], 0, 0, 0);
        }
    }

    int orow0 = blockIdx.x * 64 + wv * 16 + quad * 4;
    #pragma unroll
    for (int nt = 0; nt < 8; ++nt) {
        int col = nt * 16 + l16;
        float b = bias[col];
        #pragma unroll
        for (int r = 0; r < 4; ++r) {
            int orow = orow0 + r;
            if (orow < N_NODES) {
                float val = fmaxf(acc[nt][r] + b, 0.f);
                if (last) out_f[(size_t)orow * DIM + col] = val;
                else      out_bf[(size_t)orow * DIM + col] = f2bf(val);
            }
        }
    }
}

// ---------------------------------------------------------------------------
extern "C" void kernel_launch(void* const* d_in, const int* in_sizes, int n_in,
                              void* d_out, int out_size, void* d_ws, size_t ws_size,
                              hipStream_t stream) {
    const float* v     = (const float*)d_in[0];
    const float* e     = (const float*)d_in[1];
    const int*   src   = (const int*)  d_in[2];
    const int*   dst   = (const int*)  d_in[3];
    const float* Aw    = (const float*)d_in[4];
    const float* Ab    = (const float*)d_in[5];
    const float* rs    = (const float*)d_in[6];
    const float* sigma = (const float*)d_in[7];
    float* out = (float*)d_out;

    // ---- workspace layout (~51.5 MB) ----
    char* p = (char*)d_ws;
    int2*           meta  = (int2*)p;            p += (size_t)N_EDGES * 8;       // 12.8 MB (final CSR)
    unsigned short* bufV  = (unsigned short*)p;  p += (size_t)N_PAD * DIM * 2;   // 12.81 MB
    unsigned short* bufA  = (unsigned short*)p;  p += (size_t)N_PAD * DIM * 2;   // 12.81 MB
    unsigned short* bufB  = (unsigned short*)p;  p += (size_t)N_PAD * DIM * 2;   // 12.81 MB
    uint4*          wfrag = (uint4*)p;           p += 2048 * 16;                 //  32 KB
    int*            off   = (int*)p;             p += (size_t)(N_NODES + 1) * 4;
    int*            gtot  = (int*)p;             p += (NGROUP + 2) * 4;
    int*            goff  = (int*)p;             p += (NGROUP + 2) * 4;
    // aliases (dead before host buffer's first write):
    int2* metaT   = (int2*)bufA;                       // unsorted meta, dead after tagsort
    int*  partial = (int*)bufB;                        // NB_PRE*NGROUP = 1.6 MB
    int*  pbase   = partial + NB_PRE * NGROUP;         // 1.6 MB, dead after reorder

    convert_v_kernel<<<(N_NODES * DIM / 4 + 255) / 256, 256, 0, stream>>>(v, bufV);
    wprep_kernel<<<8, 256, 0, stream>>>(Aw, wfrag);
    countp_kernel<<<NB_PRE, 256, 0, stream>>>(dst, partial);
    sumA_kernel<<<NGROUP, 256, 0, stream>>>(partial, gtot);
    scanB_kernel<<<1, 256, 0, stream>>>(gtot, goff);
    scanC_kernel<<<NGROUP, 256, 0, stream>>>(partial, goff, pbase);
    reorder_kernel<<<NB_PRE, 256, 0, stream>>>(e, src, dst, rs, sigma, pbase, metaT);
    tagsort_kernel<<<NGROUP, 256, 0, stream>>>(metaT, goff, meta, off);

    const int GB = (N_NODES + 3) / 4;     // 12500 blocks (4 waves each)
    const int MB = N_PAD / 64;            // 782 blocks

    // L0: bufV -> bufA -> bufB ; L1: bufB -> bufA -> bufV ; L2: bufV -> bufA -> out
    gather_kernel<<<GB, 256, 0, stream>>>(bufV, v, meta, off, bufA);
    gemm_kernel<<<MB, 256, 0, stream>>>(bufA, wfrag, Ab, bufB, nullptr, 0);
    gather_kernel<<<GB, 256, 0, stream>>>(bufB, v, meta, off, bufA);
    gemm_kernel<<<MB, 256, 0, stream>>>(bufA, wfrag, Ab, bufV, nullptr, 0);
    gather_kernel<<<GB, 256, 0, stream>>>(bufV, v, meta, off, bufA);
    gemm_kernel<<<MB, 256, 0, stream>>>(bufA, wfrag, Ab, nullptr, out, 1);
}